// Round 4
// baseline (212.029 us; speedup 1.0000x reference)
//
#include <hip/hip_runtime.h>

typedef unsigned short u16;
typedef unsigned int   u32;
typedef short bf16x8 __attribute__((ext_vector_type(8)));
typedef float f32x16 __attribute__((ext_vector_type(16)));

#define S_  2048
#define D_  64
#define NR_ 4
#define NB_ 32

#define AS 72    // A tile row stride (shorts), 144 B (16B-aligned)
#define VS 136   // Vt row stride (shorts), 272 B
#define PS 136   // SM row stride (shorts), 272 B

__device__ __forceinline__ float bf2f(u16 u){ return __uint_as_float(((u32)u)<<16); }
__device__ __forceinline__ u16 f2bf(float f){
  u32 u = __float_as_uint(f);
  u32 r = (u + 0x7fffu + ((u>>16)&1u)) >> 16;
  return (u16)r;
}
// packed f32x2 -> bf16x2 (RNE). gfx950 has v_cvt_pk_bf16_f32.
__device__ __forceinline__ u32 pk2bf(float a, float b){
#if __has_builtin(__builtin_amdgcn_cvt_pk_bf16_f32)
  auto r = __builtin_amdgcn_cvt_pk_bf16_f32(a, b);
  u32 u; __builtin_memcpy(&u, &r, 4); return u;
#else
  return (u32)f2bf(a) | ((u32)f2bf(b) << 16);
#endif
}
__device__ __forceinline__ u16 f2bf1(float a){ return (u16)pk2bf(a, a); }
__device__ __forceinline__ void unpack2(u32 w, float &a, float &b){
  a = __uint_as_float(w<<16);
  b = __uint_as_float(w & 0xffff0000u);
}
__device__ __forceinline__ bf16x8 ld8(const u16* p){
  union { uint4 u; bf16x8 v; } x;
  x.u = *(const uint4*)p;
  return x.v;
}

// ---------------------------------------------------------------------------
// K1: hash (f32 exact, R via uniform scalar loads) + fused q->bf16 + key norms
// grid 256 blocks x 256 thr; b = blk>>3
// ---------------------------------------------------------------------------
__global__ __launch_bounds__(256) void k_hash(const float* __restrict__ q,
                                              const float* __restrict__ R,
                                              int* __restrict__ hout,
                                              u16* __restrict__ qb,
                                              float* __restrict__ scq){
  int b   = blockIdx.x >> 3;
  int pos = (blockIdx.x & 7) * 256 + threadIdx.x;
  const float4* R4 = (const float4*)(R + (size_t)b * 4096);   // uniform -> s_load
  const float4* q4 = (const float4*)(q + ((size_t)b * S_ + pos) * D_);

  float acc[64];
  #pragma unroll
  for (int i = 0; i < 64; i++) acc[i] = 0.f;
  u32 qp[32];
  float ss = 0.f;

  #pragma unroll
  for (int c = 0; c < 16; c++){
    float4 w = q4[c];
    ss += w.x*w.x + w.y*w.y + w.z*w.z + w.w*w.w;
    qp[c*2]   = pk2bf(w.x, w.y);
    qp[c*2+1] = pk2bf(w.z, w.w);
    float qd[4] = {w.x, w.y, w.z, w.w};
    #pragma unroll
    for (int dd = 0; dd < 4; dd++){
      int d = c * 4 + dd;
      #pragma unroll
      for (int k4 = 0; k4 < 16; k4++){
        float4 rv = R4[d*16 + k4];            // uniform address
        acc[k4*4+0] += qd[dd] * rv.x;
        acc[k4*4+1] += qd[dd] * rv.y;
        acc[k4*4+2] += qd[dd] * rv.z;
        acc[k4*4+3] += qd[dd] * rv.w;
      }
    }
  }
  { // write bf16 q row + norm factor
    uint4* dst = (uint4*)(qb + ((size_t)b * S_ + pos) * D_);
    #pragma unroll
    for (int k = 0; k < 8; k++)
      dst[k] = make_uint4(qp[4*k], qp[4*k+1], qp[4*k+2], qp[4*k+3]);
    scq[(size_t)b * S_ + pos] = rsqrtf(fmaxf(ss, 1e-12f)) * 0.125f;
  }
  #pragma unroll
  for (int r = 0; r < 4; r++){
    float bv = acc[r*16]; int bi = 0;
    #pragma unroll
    for (int m = 1; m < 32; m++){
      float v = (m < 16) ? acc[r*16 + m] : -acc[r*16 + m - 16];
      if (v > bv){ bv = v; bi = m; }   // strict >: first max wins
    }
    hout[((size_t)b * NR_ + r) * S_ + pos] = bi;
  }
}

// ---------------------------------------------------------------------------
// K1b: v -> bf16
// ---------------------------------------------------------------------------
__global__ __launch_bounds__(256) void k_prepv(const float* __restrict__ v,
                                               u16* __restrict__ vb){
  size_t idx = (size_t)blockIdx.x * 256 + threadIdx.x;   // over B*S*D/4
  float4 f = ((const float4*)v)[idx];
  ((uint2*)vb)[idx] = make_uint2(pk2bf(f.x, f.y), pk2bf(f.z, f.w));
}

// ---------------------------------------------------------------------------
// K2: stable counting sort on 32 bins per (b,r).
// ---------------------------------------------------------------------------
__global__ __launch_bounds__(256) void k_sort(const int* __restrict__ h,
                                              int* __restrict__ sidx,
                                              int* __restrict__ chk){
  __shared__ int cnt[32][257];
  __shared__ int base[32];
  int br = blockIdx.x;
  const int* hb = h + (size_t)br * S_;
  int t = threadIdx.x;

  #pragma unroll
  for (int hh = 0; hh < 32; hh++) cnt[hh][t] = 0;
  __syncthreads();

  int hv[8];
  const int4* hb4 = (const int4*)hb;
  int4 a0 = hb4[t*2], a1 = hb4[t*2+1];
  hv[0]=a0.x; hv[1]=a0.y; hv[2]=a0.z; hv[3]=a0.w;
  hv[4]=a1.x; hv[5]=a1.y; hv[6]=a1.z; hv[7]=a1.w;
  #pragma unroll
  for (int k = 0; k < 8; k++) cnt[hv[k]][t]++;
  __syncthreads();

  int wave = t >> 6, lane = t & 63;
  for (int hh = wave*8; hh < wave*8 + 8; hh++){
    int vals[4]; int s0 = 0;
    #pragma unroll
    for (int k = 0; k < 4; k++){ vals[k] = cnt[hh][lane*4+k]; s0 += vals[k]; }
    int incl = s0;
    #pragma unroll
    for (int off = 1; off < 64; off <<= 1){
      int o = __shfl_up(incl, off, 64);
      if (lane >= off) incl += o;
    }
    int run = incl - s0;
    #pragma unroll
    for (int k = 0; k < 4; k++){ int tmp = vals[k]; cnt[hh][lane*4+k] = run; run += tmp; }
    if (lane == 63) base[hh] = incl;
  }
  __syncthreads();
  if (t == 0){
    int run = 0;
    #pragma unroll
    for (int hh = 0; hh < 32; hh++){ int tot = base[hh]; base[hh] = run; run += tot; }
  }
  __syncthreads();

  int p0 = t * 8;
  #pragma unroll
  for (int k = 0; k < 8; k++){
    int hh = hv[k];
    int c = cnt[hh][t];
    int slot = base[hh] + c;
    cnt[hh][t] = c + 1;
    sidx[(size_t)br * S_ + slot]    = p0 + k;
    chk [(size_t)br * S_ + p0 + k]  = slot >> 6;
  }
}

// ---------------------------------------------------------------------------
// K3: per (b, r, bucket n): MFMA attention on pre-converted bf16 q/v.
// ---------------------------------------------------------------------------
__global__ __launch_bounds__(256, 4) void k_attn(const u16* __restrict__ qb,
                                                 const u16* __restrict__ vb,
                                                 const int* __restrict__ sidx,
                                                 const int* __restrict__ chk,
                                                 const float* __restrict__ scq,
                                                 float* __restrict__ lse_ws,
                                                 u16*  __restrict__ att_ws){
  __shared__ u16 A[128*AS];      // Q/K tile row-major; later Vt[64][VS] (d-major)
  __shared__ u16 SM[64*PS];      // logits -> probs (bf16)
  __shared__ int   pkey[128];
  __shared__ float rcnt[128];
  __shared__ float sc[128];

  int blk = blockIdx.x;
  int b = blk >> 7, r = (blk >> 5) & 3, n = blk & 31;
  int npv = (n + 31) & 31;
  int t = threadIdx.x;
  int lane = t & 63, w = t >> 6;
  const int* sb = sidx + ((size_t)b * NR_ + r) * S_;

  if (t < 128){
    int p = (t < 64) ? sb[npv*64 + t] : sb[n*64 + (t - 64)];
    pkey[t] = p;
    int c = 0;
    #pragma unroll
    for (int rr = 0; rr < 4; rr++){
      int ch = chk[((size_t)b * NR_ + rr) * S_ + p];
      c += (ch == n) || (ch == npv);
    }
    if (c < 1) c = 1;
    rcnt[t] = 1.0f / (float)c;
    sc[t] = scq[(size_t)b * S_ + p];
  }
  __syncthreads();

  // ---- phase 1: stage Q/K bf16 rows; early V column gather ----------------
  {
    int row = t >> 1, half = t & 1;
    const uint4* src = (const uint4*)(qb + ((size_t)b*S_ + pkey[row])*D_) + half*4;
    uint4* dst = (uint4*)(&A[row*AS + half*32]);
    #pragma unroll
    for (int k = 0; k < 4; k++) dst[k] = src[k];
  }
  int jp = t & 63, dgrp = t >> 6;   // V: key pair (2jp,2jp+1), d-range dgrp*16..+15
  uint4 va0, va1, vb0, vb1;
  {
    const uint4* s0 = (const uint4*)(vb + ((size_t)b*S_ + pkey[2*jp  ])*D_ + dgrp*16);
    const uint4* s1 = (const uint4*)(vb + ((size_t)b*S_ + pkey[2*jp+1])*D_ + dgrp*16);
    va0 = s0[0]; va1 = s0[1]; vb0 = s1[0]; vb1 = s1[1];
  }
  __syncthreads();

  // ---- phase 2: S = Q.K^T via MFMA ----------------------------------------
  int Mt = w & 1, Nt0 = (w >> 1) * 2;
  f32x16 acc0, acc1;
  #pragma unroll
  for (int i = 0; i < 16; i++){ acc0[i] = 0.f; acc1[i] = 0.f; }
  {
    int mrow  = (64 + Mt*32 + (lane & 31)) * AS;
    int krow0 = (Nt0*32 + (lane & 31)) * AS;
    int krow1 = krow0 + 32*AS;
    int coff  = (lane >> 5) * 8;
    #pragma unroll
    for (int ks = 0; ks < 4; ks++){
      int o = ks*16 + coff;
      bf16x8 af = ld8(&A[mrow  + o]);
      bf16x8 b0 = ld8(&A[krow0 + o]);
      bf16x8 b1 = ld8(&A[krow1 + o]);
      acc0 = __builtin_amdgcn_mfma_f32_32x32x16_bf16(af, b0, acc0, 0, 0, 0);
      acc1 = __builtin_amdgcn_mfma_f32_32x32x16_bf16(af, b1, acc1, 0, 0, 0);
    }
  }
  { // masks + scale, store bf16 logits to SM
    int h = lane >> 5;
    int pi[16];
    #pragma unroll
    for (int reg = 0; reg < 16; reg++){
      int il = (reg & 3) + 8*(reg >> 2) + 4*h;
      pi[reg] = pkey[64 + Mt*32 + il];
    }
    #pragma unroll
    for (int e = 0; e < 2; e++){
      int j = (Nt0 + e)*32 + (lane & 31);
      int pj = pkey[j];
      float scj = sc[j];
      #pragma unroll
      for (int reg = 0; reg < 16; reg++){
        int il = (reg & 3) + 8*(reg >> 2) + 4*h;
        float l = (e ? acc1[reg] : acc0[reg]) * scj;
        if (pi[reg] < pj)       l = -1000000000.0f;
        else if (pi[reg] == pj) l = -100000.0f;
        SM[(Mt*32 + il)*PS + j] = f2bf1(l);
      }
    }
  }
  __syncthreads();

  // ---- phase 3: row softmax (4 threads/row, single-exp), rcnt fold, lse ---
  {
    int srow = t >> 2, seg = t & 3;
    uint4 u[4];
    const uint4* p4 = (const uint4*)(&SM[srow*PS + seg*32]);
    #pragma unroll
    for (int k = 0; k < 4; k++) u[k] = p4[k];
    float vals[32];
    #pragma unroll
    for (int k = 0; k < 4; k++){
      unpack2(u[k].x, vals[k*8+0], vals[k*8+1]);
      unpack2(u[k].y, vals[k*8+2], vals[k*8+3]);
      unpack2(u[k].z, vals[k*8+4], vals[k*8+5]);
      unpack2(u[k].w, vals[k*8+6], vals[k*8+7]);
    }
    float mx = -3.0e38f;
    #pragma unroll
    for (int k = 0; k < 32; k++) mx = fmaxf(mx, vals[k]);
    float sl = 0.f;
    #pragma unroll
    for (int k = 0; k < 32; k++){ vals[k] = __expf(vals[k] - mx); sl += vals[k]; }
    float mxg = fmaxf(mx, __shfl_xor(mx, 1, 64));
    mxg = fmaxf(mxg, __shfl_xor(mxg, 2, 64));
    float scale = __expf(mx - mxg);
    float s = sl * scale;
    s += __shfl_xor(s, 1, 64);
    s += __shfl_xor(s, 2, 64);
    float f = scale / s;
    const float4* rc4 = (const float4*)(&rcnt[seg*32]);
    u32 ob[16];
    #pragma unroll
    for (int k4 = 0; k4 < 8; k4++){
      float4 rc = rc4[k4];
      ob[k4*2+0] = pk2bf(vals[k4*4+0]*f*rc.x, vals[k4*4+1]*f*rc.y);
      ob[k4*2+1] = pk2bf(vals[k4*4+2]*f*rc.z, vals[k4*4+3]*f*rc.w);
    }
    uint4* d4 = (uint4*)(&SM[srow*PS + seg*32]);
    #pragma unroll
    for (int k = 0; k < 4; k++)
      d4[k] = make_uint4(ob[4*k], ob[4*k+1], ob[4*k+2], ob[4*k+3]);
    if (seg == 0)
      lse_ws[((size_t)b*S_ + pkey[64 + srow])*NR_ + r] = mxg + __logf(s);
  }

  // ---- phase 4: Vt = V^T (pure bf16 interleave), overwriting A ------------
  {
    u32 au[8] = {va0.x, va0.y, va0.z, va0.w, va1.x, va1.y, va1.z, va1.w};
    u32 bu[8] = {vb0.x, vb0.y, vb0.z, vb0.w, vb1.x, vb1.y, vb1.z, vb1.w};
    u32* vtp = (u32*)A;
    #pragma unroll
    for (int k = 0; k < 8; k++){
      int d0 = dgrp*16 + 2*k;
      u32 even = (au[k] & 0xffffu) | (bu[k] << 16);
      u32 odd  = (au[k] >> 16)     | (bu[k] & 0xffff0000u);
      vtp[ d0      * (VS/2) + jp] = even;
      vtp[(d0 + 1) * (VS/2) + jp] = odd;
    }
  }
  __syncthreads();

  // ---- phase 5: out = P.V via MFMA, scatter bf16 --------------------------
  {
    int Mt2 = w >> 1, Nt2 = w & 1;
    f32x16 acc;
    #pragma unroll
    for (int i = 0; i < 16; i++) acc[i] = 0.f;
    int prow = (Mt2*32 + (lane & 31)) * PS;
    int vrow = (Nt2*32 + (lane & 31)) * VS;
    int coff = (lane >> 5) * 8;
    #pragma unroll
    for (int ks = 0; ks < 8; ks++){
      int o = ks*16 + coff;
      bf16x8 af = ld8(&SM[prow + o]);
      bf16x8 bf = ld8(&A[vrow + o]);
      acc = __builtin_amdgcn_mfma_f32_32x32x16_bf16(af, bf, acc, 0, 0, 0);
    }
    int h = lane >> 5;
    int dcol = Nt2*32 + (lane & 31);
    #pragma unroll
    for (int reg = 0; reg < 16; reg++){
      int il = (reg & 3) + 8*(reg >> 2) + 4*h;
      int p = pkey[64 + Mt2*32 + il];
      att_ws[(((size_t)b*S_ + p)*NR_ + r)*D_ + dcol] = f2bf1(acc[reg]);
    }
  }
}

// ---------------------------------------------------------------------------
// K4: per position softmax over round LSEs, weighted sum of round outputs
// ---------------------------------------------------------------------------
__global__ __launch_bounds__(256) void k_comb(const float* __restrict__ lse_ws,
                                              const u16* __restrict__ att_ws,
                                              float* __restrict__ out){
  size_t idx = (size_t)blockIdx.x * 256 + threadIdx.x;   // over B*S*D
  size_t pd = idx >> 6;
  int d = (int)(idx & 63);
  float4 lv = *(const float4*)(lse_ws + pd * 4);
  float m = fmaxf(fmaxf(lv.x, lv.y), fmaxf(lv.z, lv.w));
  float e0 = __expf(lv.x - m), e1 = __expf(lv.y - m);
  float e2 = __expf(lv.z - m), e3 = __expf(lv.w - m);
  float inv = 1.0f / (e0 + e1 + e2 + e3);
  const u16* a = att_ws + pd * 256 + d;
  float o = (bf2f(a[0])   * e0 + bf2f(a[64])  * e1 +
             bf2f(a[128]) * e2 + bf2f(a[192]) * e3) * inv;
  out[idx] = o;
}

// ---------------------------------------------------------------------------
extern "C" void kernel_launch(void* const* d_in, const int* in_sizes, int n_in,
                              void* d_out, int out_size, void* d_ws, size_t ws_size,
                              hipStream_t stream){
  const float* q = (const float*)d_in[0];   // (32,2048,64) f32
  const float* v = (const float*)d_in[1];   // (32,2048,64) f32
  const float* R = (const float*)d_in[2];   // (32,64,4,16) f32

  char* w = (char*)d_ws;
  int*   h    = (int*)  (w + 0);                     // 1 MB
  int*   sidx = (int*)  (w + (size_t)(1u << 20));    // 1 MB
  int*   chkA = (int*)  (w + (size_t)(2u << 20));    // 1 MB
  float* lse  = (float*)(w + (size_t)(3u << 20));    // 1 MB
  u16*   att  = (u16*)  (w + (size_t)(4u << 20));    // 32 MB
  u16*   qb   = (u16*)  (w + (size_t)(36u << 20));   // 8 MB bf16 q
  u16*   vbuf = (u16*)  (w + (size_t)(44u << 20));   // 8 MB bf16 v
  float* scq  = (float*)(w + (size_t)(52u << 20));   // 256 KB
  float* out  = (float*)d_out;

  k_hash <<<256,  256, 0, stream>>>(q, R, h, qb, scq);
  k_prepv<<<4096, 256, 0, stream>>>(v, vbuf);
  k_sort <<<128,  256, 0, stream>>>(h, sidx, chkA);
  k_attn <<<4096, 256, 0, stream>>>(qb, vbuf, sidx, chkA, scq, lse, att);
  k_comb <<<16384,256, 0, stream>>>(lse, att, out);
}

// Round 5
// 154.836 us; speedup vs baseline: 1.3694x; 1.3694x over previous
//
#include <hip/hip_runtime.h>

typedef unsigned short u16;
typedef unsigned int   u32;
typedef short bf16x8 __attribute__((ext_vector_type(8)));
typedef float f32x16 __attribute__((ext_vector_type(16)));

#define S_  2048
#define D_  64
#define NR_ 4
#define NB_ 32

#define AS 72    // A tile row stride (shorts), 144 B (16B-aligned)
#define VS 136   // Vt row stride (shorts), 272 B
#define PS 136   // SM row stride (shorts), 272 B

__device__ __forceinline__ float bf2f(u16 u){ return __uint_as_float(((u32)u)<<16); }
__device__ __forceinline__ u16 f2bf(float f){
  u32 u = __float_as_uint(f);
  u32 r = (u + 0x7fffu + ((u>>16)&1u)) >> 16;
  return (u16)r;
}
// packed f32x2 -> bf16x2 (RNE). gfx950 has v_cvt_pk_bf16_f32.
__device__ __forceinline__ u32 pk2bf(float a, float b){
#if __has_builtin(__builtin_amdgcn_cvt_pk_bf16_f32)
  auto r = __builtin_amdgcn_cvt_pk_bf16_f32(a, b);
  u32 u; __builtin_memcpy(&u, &r, 4); return u;
#else
  return (u32)f2bf(a) | ((u32)f2bf(b) << 16);
#endif
}
__device__ __forceinline__ u16 f2bf1(float a){ return (u16)pk2bf(a, a); }
__device__ __forceinline__ void unpack2(u32 w, float &a, float &b){
  a = __uint_as_float(w<<16);
  b = __uint_as_float(w & 0xffff0000u);
}
__device__ __forceinline__ bf16x8 ld8(const u16* p){
  union { uint4 u; bf16x8 v; } x;
  x.u = *(const uint4*)p;
  return x.v;
}

// ---------------------------------------------------------------------------
// K1: hash via LDS-broadcast R, 2 positions/thread; fused q->bf16, v->bf16,
// key norms. grid 256 blocks x 128 thr; block covers 256 positions.
// ---------------------------------------------------------------------------
__global__ __launch_bounds__(128) void k_hash(const float* __restrict__ q,
                                              const float* __restrict__ v,
                                              const float* __restrict__ R,
                                              int* __restrict__ hout,
                                              u16* __restrict__ qb,
                                              u16* __restrict__ vbuf,
                                              float* __restrict__ scq){
  __shared__ float Rl[4096];               // [d][r*16+k] row-major, f32
  int b    = blockIdx.x >> 3;
  int pos0 = (blockIdx.x & 7) * 256 + threadIdx.x;   // and pos0+128
  int pos1 = pos0 + 128;

  { // stage R (coalesced)
    const float4* Rg = (const float4*)(R + (size_t)b * 4096);
    float4* Rs = (float4*)Rl;
    #pragma unroll
    for (int k = 0; k < 8; k++) Rs[k*128 + threadIdx.x] = Rg[k*128 + threadIdx.x];
  }
  __syncthreads();

  const float4* q40 = (const float4*)(q + ((size_t)b * S_ + pos0) * D_);
  const float4* q41 = (const float4*)(q + ((size_t)b * S_ + pos1) * D_);
  const float4* v40 = (const float4*)(v + ((size_t)b * S_ + pos0) * D_);
  const float4* v41 = (const float4*)(v + ((size_t)b * S_ + pos1) * D_);
  uint2* qw0 = (uint2*)(qb   + ((size_t)b * S_ + pos0) * D_);
  uint2* qw1 = (uint2*)(qb   + ((size_t)b * S_ + pos1) * D_);
  uint2* vw0 = (uint2*)(vbuf + ((size_t)b * S_ + pos0) * D_);
  uint2* vw1 = (uint2*)(vbuf + ((size_t)b * S_ + pos1) * D_);

  float acc0[64], acc1[64];
  #pragma unroll
  for (int i = 0; i < 64; i++){ acc0[i] = 0.f; acc1[i] = 0.f; }
  float ss0 = 0.f, ss1 = 0.f;

  #pragma unroll 4
  for (int c = 0; c < 16; c++){
    float4 wa = q40[c], wb = q41[c];
    float4 xa = v40[c], xb = v41[c];
    ss0 += wa.x*wa.x + wa.y*wa.y + wa.z*wa.z + wa.w*wa.w;
    ss1 += wb.x*wb.x + wb.y*wb.y + wb.z*wb.z + wb.w*wb.w;
    qw0[c] = make_uint2(pk2bf(wa.x, wa.y), pk2bf(wa.z, wa.w));
    qw1[c] = make_uint2(pk2bf(wb.x, wb.y), pk2bf(wb.z, wb.w));
    vw0[c] = make_uint2(pk2bf(xa.x, xa.y), pk2bf(xa.z, xa.w));
    vw1[c] = make_uint2(pk2bf(xb.x, xb.y), pk2bf(xb.z, xb.w));
    float qa[4] = {wa.x, wa.y, wa.z, wa.w};
    float qb_[4] = {wb.x, wb.y, wb.z, wb.w};
    #pragma unroll
    for (int dd = 0; dd < 4; dd++){
      int d = c * 4 + dd;
      const float4* Rr = (const float4*)(&Rl[d * 64]);
      #pragma unroll
      for (int k4 = 0; k4 < 16; k4++){
        float4 rv = Rr[k4];      // broadcast (same addr all lanes) — conflict-free
        acc0[k4*4+0] += qa[dd] * rv.x;  acc1[k4*4+0] += qb_[dd] * rv.x;
        acc0[k4*4+1] += qa[dd] * rv.y;  acc1[k4*4+1] += qb_[dd] * rv.y;
        acc0[k4*4+2] += qa[dd] * rv.z;  acc1[k4*4+2] += qb_[dd] * rv.z;
        acc0[k4*4+3] += qa[dd] * rv.w;  acc1[k4*4+3] += qb_[dd] * rv.w;
      }
    }
  }
  scq[(size_t)b * S_ + pos0] = rsqrtf(fmaxf(ss0, 1e-12f)) * 0.125f;
  scq[(size_t)b * S_ + pos1] = rsqrtf(fmaxf(ss1, 1e-12f)) * 0.125f;

  #pragma unroll
  for (int r = 0; r < 4; r++){
    float bv0 = acc0[r*16]; int bi0 = 0;
    float bv1 = acc1[r*16]; int bi1 = 0;
    #pragma unroll
    for (int m = 1; m < 32; m++){
      float v0 = (m < 16) ? acc0[r*16 + m] : -acc0[r*16 + m - 16];
      float v1 = (m < 16) ? acc1[r*16 + m] : -acc1[r*16 + m - 16];
      if (v0 > bv0){ bv0 = v0; bi0 = m; }   // strict >: first max wins
      if (v1 > bv1){ bv1 = v1; bi1 = m; }
    }
    hout[((size_t)b * NR_ + r) * S_ + pos0] = bi0;
    hout[((size_t)b * NR_ + r) * S_ + pos1] = bi1;
  }
}

// ---------------------------------------------------------------------------
// K2: stable counting sort on 32 bins per (b,r).
// ---------------------------------------------------------------------------
__global__ __launch_bounds__(256) void k_sort(const int* __restrict__ h,
                                              int* __restrict__ sidx,
                                              int* __restrict__ chk){
  __shared__ int cnt[32][257];
  __shared__ int base[32];
  int br = blockIdx.x;
  const int* hb = h + (size_t)br * S_;
  int t = threadIdx.x;

  #pragma unroll
  for (int hh = 0; hh < 32; hh++) cnt[hh][t] = 0;
  __syncthreads();

  int hv[8];
  const int4* hb4 = (const int4*)hb;
  int4 a0 = hb4[t*2], a1 = hb4[t*2+1];
  hv[0]=a0.x; hv[1]=a0.y; hv[2]=a0.z; hv[3]=a0.w;
  hv[4]=a1.x; hv[5]=a1.y; hv[6]=a1.z; hv[7]=a1.w;
  #pragma unroll
  for (int k = 0; k < 8; k++) cnt[hv[k]][t]++;
  __syncthreads();

  int wave = t >> 6, lane = t & 63;
  for (int hh = wave*8; hh < wave*8 + 8; hh++){
    int vals[4]; int s0 = 0;
    #pragma unroll
    for (int k = 0; k < 4; k++){ vals[k] = cnt[hh][lane*4+k]; s0 += vals[k]; }
    int incl = s0;
    #pragma unroll
    for (int off = 1; off < 64; off <<= 1){
      int o = __shfl_up(incl, off, 64);
      if (lane >= off) incl += o;
    }
    int run = incl - s0;
    #pragma unroll
    for (int k = 0; k < 4; k++){ int tmp = vals[k]; cnt[hh][lane*4+k] = run; run += tmp; }
    if (lane == 63) base[hh] = incl;
  }
  __syncthreads();
  if (t == 0){
    int run = 0;
    #pragma unroll
    for (int hh = 0; hh < 32; hh++){ int tot = base[hh]; base[hh] = run; run += tot; }
  }
  __syncthreads();

  int p0 = t * 8;
  #pragma unroll
  for (int k = 0; k < 8; k++){
    int hh = hv[k];
    int c = cnt[hh][t];
    int slot = base[hh] + c;
    cnt[hh][t] = c + 1;
    sidx[(size_t)br * S_ + slot]    = p0 + k;
    chk [(size_t)br * S_ + p0 + k]  = slot >> 6;
  }
}

// ---------------------------------------------------------------------------
// K3: per (b, r, bucket n): MFMA attention on pre-converted bf16 q/v.
// ---------------------------------------------------------------------------
__global__ __launch_bounds__(256, 4) void k_attn(const u16* __restrict__ qb,
                                                 const u16* __restrict__ vb,
                                                 const int* __restrict__ sidx,
                                                 const int* __restrict__ chk,
                                                 const float* __restrict__ scq,
                                                 float* __restrict__ lse_ws,
                                                 u16*  __restrict__ att_ws){
  __shared__ u16 A[128*AS];      // Q/K tile row-major; later Vt[64][VS] (d-major)
  __shared__ u16 SM[64*PS];      // logits -> probs (bf16)
  __shared__ int   pkey[128];
  __shared__ float rcnt[128];
  __shared__ float sc[128];

  int blk = blockIdx.x;
  int b = blk >> 7, r = (blk >> 5) & 3, n = blk & 31;
  int npv = (n + 31) & 31;
  int t = threadIdx.x;
  int lane = t & 63, w = t >> 6;
  const int* sb = sidx + ((size_t)b * NR_ + r) * S_;

  if (t < 128){
    int p = (t < 64) ? sb[npv*64 + t] : sb[n*64 + (t - 64)];
    pkey[t] = p;
    int c = 0;
    #pragma unroll
    for (int rr = 0; rr < 4; rr++){
      int ch = chk[((size_t)b * NR_ + rr) * S_ + p];
      c += (ch == n) || (ch == npv);
    }
    if (c < 1) c = 1;
    rcnt[t] = 1.0f / (float)c;
    sc[t] = scq[(size_t)b * S_ + p];
  }
  __syncthreads();

  // ---- phase 1: stage Q/K bf16 rows; early V column gather ----------------
  {
    int row = t >> 1, half = t & 1;
    const uint4* src = (const uint4*)(qb + ((size_t)b*S_ + pkey[row])*D_) + half*4;
    uint4* dst = (uint4*)(&A[row*AS + half*32]);
    #pragma unroll
    for (int k = 0; k < 4; k++) dst[k] = src[k];
  }
  int jp = t & 63, dgrp = t >> 6;   // V: key pair (2jp,2jp+1), d-range dgrp*16..+15
  uint4 va0, va1, vb0, vb1;
  {
    const uint4* s0 = (const uint4*)(vb + ((size_t)b*S_ + pkey[2*jp  ])*D_ + dgrp*16);
    const uint4* s1 = (const uint4*)(vb + ((size_t)b*S_ + pkey[2*jp+1])*D_ + dgrp*16);
    va0 = s0[0]; va1 = s0[1]; vb0 = s1[0]; vb1 = s1[1];
  }
  __syncthreads();

  // ---- phase 2: S = Q.K^T via MFMA ----------------------------------------
  int Mt = w & 1, Nt0 = (w >> 1) * 2;
  f32x16 acc0, acc1;
  #pragma unroll
  for (int i = 0; i < 16; i++){ acc0[i] = 0.f; acc1[i] = 0.f; }
  {
    int mrow  = (64 + Mt*32 + (lane & 31)) * AS;
    int krow0 = (Nt0*32 + (lane & 31)) * AS;
    int krow1 = krow0 + 32*AS;
    int coff  = (lane >> 5) * 8;
    #pragma unroll
    for (int ks = 0; ks < 4; ks++){
      int o = ks*16 + coff;
      bf16x8 af = ld8(&A[mrow  + o]);
      bf16x8 b0 = ld8(&A[krow0 + o]);
      bf16x8 b1 = ld8(&A[krow1 + o]);
      acc0 = __builtin_amdgcn_mfma_f32_32x32x16_bf16(af, b0, acc0, 0, 0, 0);
      acc1 = __builtin_amdgcn_mfma_f32_32x32x16_bf16(af, b1, acc1, 0, 0, 0);
    }
  }
  { // masks + scale, store bf16 logits to SM
    int h = lane >> 5;
    int pi[16];
    #pragma unroll
    for (int reg = 0; reg < 16; reg++){
      int il = (reg & 3) + 8*(reg >> 2) + 4*h;
      pi[reg] = pkey[64 + Mt*32 + il];
    }
    #pragma unroll
    for (int e = 0; e < 2; e++){
      int j = (Nt0 + e)*32 + (lane & 31);
      int pj = pkey[j];
      float scj = sc[j];
      #pragma unroll
      for (int reg = 0; reg < 16; reg++){
        int il = (reg & 3) + 8*(reg >> 2) + 4*h;
        float l = (e ? acc1[reg] : acc0[reg]) * scj;
        if (pi[reg] < pj)       l = -1000000000.0f;
        else if (pi[reg] == pj) l = -100000.0f;
        SM[(Mt*32 + il)*PS + j] = f2bf1(l);
      }
    }
  }
  __syncthreads();

  // ---- phase 3: row softmax (4 threads/row, single-exp), rcnt fold, lse ---
  {
    int srow = t >> 2, seg = t & 3;
    uint4 u[4];
    const uint4* p4 = (const uint4*)(&SM[srow*PS + seg*32]);
    #pragma unroll
    for (int k = 0; k < 4; k++) u[k] = p4[k];
    float vals[32];
    #pragma unroll
    for (int k = 0; k < 4; k++){
      unpack2(u[k].x, vals[k*8+0], vals[k*8+1]);
      unpack2(u[k].y, vals[k*8+2], vals[k*8+3]);
      unpack2(u[k].z, vals[k*8+4], vals[k*8+5]);
      unpack2(u[k].w, vals[k*8+6], vals[k*8+7]);
    }
    float mx = -3.0e38f;
    #pragma unroll
    for (int k = 0; k < 32; k++) mx = fmaxf(mx, vals[k]);
    float sl = 0.f;
    #pragma unroll
    for (int k = 0; k < 32; k++){ vals[k] = __expf(vals[k] - mx); sl += vals[k]; }
    float mxg = fmaxf(mx, __shfl_xor(mx, 1, 64));
    mxg = fmaxf(mxg, __shfl_xor(mxg, 2, 64));
    float scale = __expf(mx - mxg);
    float s = sl * scale;
    s += __shfl_xor(s, 1, 64);
    s += __shfl_xor(s, 2, 64);
    float f = scale / s;
    const float4* rc4 = (const float4*)(&rcnt[seg*32]);
    u32 ob[16];
    #pragma unroll
    for (int k4 = 0; k4 < 8; k4++){
      float4 rc = rc4[k4];
      ob[k4*2+0] = pk2bf(vals[k4*4+0]*f*rc.x, vals[k4*4+1]*f*rc.y);
      ob[k4*2+1] = pk2bf(vals[k4*4+2]*f*rc.z, vals[k4*4+3]*f*rc.w);
    }
    uint4* d4 = (uint4*)(&SM[srow*PS + seg*32]);
    #pragma unroll
    for (int k = 0; k < 4; k++)
      d4[k] = make_uint4(ob[4*k], ob[4*k+1], ob[4*k+2], ob[4*k+3]);
    if (seg == 0)
      lse_ws[((size_t)b*S_ + pkey[64 + srow])*NR_ + r] = mxg + __logf(s);
  }

  // ---- phase 4: Vt = V^T (pure bf16 interleave), overwriting A ------------
  {
    u32 au[8] = {va0.x, va0.y, va0.z, va0.w, va1.x, va1.y, va1.z, va1.w};
    u32 bu[8] = {vb0.x, vb0.y, vb0.z, vb0.w, vb1.x, vb1.y, vb1.z, vb1.w};
    u32* vtp = (u32*)A;
    #pragma unroll
    for (int k = 0; k < 8; k++){
      int d0 = dgrp*16 + 2*k;
      u32 even = (au[k] & 0xffffu) | (bu[k] << 16);
      u32 odd  = (au[k] >> 16)     | (bu[k] & 0xffff0000u);
      vtp[ d0      * (VS/2) + jp] = even;
      vtp[(d0 + 1) * (VS/2) + jp] = odd;
    }
  }
  __syncthreads();

  // ---- phase 5: out = P.V via MFMA, scatter bf16 --------------------------
  {
    int Mt2 = w >> 1, Nt2 = w & 1;
    f32x16 acc;
    #pragma unroll
    for (int i = 0; i < 16; i++) acc[i] = 0.f;
    int prow = (Mt2*32 + (lane & 31)) * PS;
    int vrow = (Nt2*32 + (lane & 31)) * VS;
    int coff = (lane >> 5) * 8;
    #pragma unroll
    for (int ks = 0; ks < 8; ks++){
      int o = ks*16 + coff;
      bf16x8 af = ld8(&SM[prow + o]);
      bf16x8 bf = ld8(&A[vrow + o]);
      acc = __builtin_amdgcn_mfma_f32_32x32x16_bf16(af, bf, acc, 0, 0, 0);
    }
    int h = lane >> 5;
    int dcol = Nt2*32 + (lane & 31);
    #pragma unroll
    for (int reg = 0; reg < 16; reg++){
      int il = (reg & 3) + 8*(reg >> 2) + 4*h;
      int p = pkey[64 + Mt2*32 + il];
      att_ws[(((size_t)b*S_ + p)*NR_ + r)*D_ + dcol] = f2bf1(acc[reg]);
    }
  }
}

// ---------------------------------------------------------------------------
// K4: per position softmax over round LSEs, weighted sum of round outputs
// ---------------------------------------------------------------------------
__global__ __launch_bounds__(256) void k_comb(const float* __restrict__ lse_ws,
                                              const u16* __restrict__ att_ws,
                                              float* __restrict__ out){
  size_t idx = (size_t)blockIdx.x * 256 + threadIdx.x;   // over B*S*D
  size_t pd = idx >> 6;
  int d = (int)(idx & 63);
  float4 lv = *(const float4*)(lse_ws + pd * 4);
  float m = fmaxf(fmaxf(lv.x, lv.y), fmaxf(lv.z, lv.w));
  float e0 = __expf(lv.x - m), e1 = __expf(lv.y - m);
  float e2 = __expf(lv.z - m), e3 = __expf(lv.w - m);
  float inv = 1.0f / (e0 + e1 + e2 + e3);
  const u16* a = att_ws + pd * 256 + d;
  float o = (bf2f(a[0])   * e0 + bf2f(a[64])  * e1 +
             bf2f(a[128]) * e2 + bf2f(a[192]) * e3) * inv;
  out[idx] = o;
}

// ---------------------------------------------------------------------------
extern "C" void kernel_launch(void* const* d_in, const int* in_sizes, int n_in,
                              void* d_out, int out_size, void* d_ws, size_t ws_size,
                              hipStream_t stream){
  const float* q = (const float*)d_in[0];   // (32,2048,64) f32
  const float* v = (const float*)d_in[1];   // (32,2048,64) f32
  const float* R = (const float*)d_in[2];   // (32,64,4,16) f32

  char* w = (char*)d_ws;
  int*   h    = (int*)  (w + 0);                     // 1 MB
  int*   sidx = (int*)  (w + (size_t)(1u << 20));    // 1 MB
  int*   chkA = (int*)  (w + (size_t)(2u << 20));    // 1 MB
  float* lse  = (float*)(w + (size_t)(3u << 20));    // 1 MB
  u16*   att  = (u16*)  (w + (size_t)(4u << 20));    // 32 MB
  u16*   qb   = (u16*)  (w + (size_t)(36u << 20));   // 8 MB bf16 q
  u16*   vbuf = (u16*)  (w + (size_t)(44u << 20));   // 8 MB bf16 v
  float* scq  = (float*)(w + (size_t)(52u << 20));   // 256 KB
  float* out  = (float*)d_out;

  k_hash <<<256,  128, 0, stream>>>(q, v, R, h, qb, vbuf, scq);
  k_sort <<<128,  256, 0, stream>>>(h, sidx, chkA);
  k_attn <<<4096, 256, 0, stream>>>(qb, vbuf, sidx, chkA, scq, lse, att);
  k_comb <<<16384,256, 0, stream>>>(lse, att, out);
}